// Round 14
// baseline (138.674 us; speedup 1.0000x reference)
//
#include <hip/hip_runtime.h>
#include <hip/hip_bf16.h>
#include <stdint.h>

using bf16x8 = __attribute__((ext_vector_type(8))) short;
using f32x4  = __attribute__((ext_vector_type(4))) float;

#define N_NODES  50000
#define K1       768
#define D1       512
#define NPAIR    16384
#define NOUT     97
#define NOUT_PAD 112
#define BM       128
#define BN       256
#define MT1      391                 // ceil(50000/128)
#define NT2      2                   // 512/256
#define NWG1     (MT1 * NT2)         // 782
#define WGPX1    98                  // ceil(782/8)
#define HALVES   24                  // 768/32 half-K-steps

__device__ __forceinline__ uint16_t f2bf(float f) {
    uint32_t u = __builtin_bit_cast(uint32_t, f);
    return (uint16_t)((u + 0x7fffu + ((u >> 16) & 1u)) >> 16);  // RNE
}

__device__ __forceinline__ uint32_t cvt_pk_bf16(float lo, float hi) {
    uint32_t r;
    asm("v_cvt_pk_bf16_f32 %0, %1, %2" : "=v"(r) : "v"(lo), "v"(hi));
    return r;
}

// async global->LDS DMA, 16B/lane; LDS dest = wave-uniform base + lane*16
__device__ __forceinline__ void gll16(const void* g, void* l) {
    __builtin_amdgcn_global_load_lds(
        (const __attribute__((address_space(1))) void*)g,
        (__attribute__((address_space(3))) void*)l, 16, 0, 0);
}

// ---- convert: W1[768][512] -> W1t bf16 [512][768]; Wp[1024][97] -> Wpt bf16 [112][1024] ----
__global__ void k_convert(const float* __restrict__ W1, const float* __restrict__ Wp,
                          uint16_t* __restrict__ W1t, uint16_t* __restrict__ Wpt) {
    int idx = blockIdx.x * 256 + threadIdx.x;
    const int n1 = D1 * K1;
    if (idx < n1) {
        int c = idx / K1, k = idx - c * K1;
        W1t[idx] = f2bf(W1[k * D1 + c]);
    } else {
        int j = idx - n1;
        if (j < NOUT_PAD * 1024) {
            int c = j >> 10, k = j & 1023;
            Wpt[j] = (c < NOUT) ? f2bf(Wp[k * NOUT + c]) : (uint16_t)0;
        }
    }
}

// ---- GEMM1: H[50000][512] = relu(A @ W1 + b1) ----
// m201-style deep pipeline: 128x256 tile, BK=32 half-steps, 4 half-buffers
// (128KB LDS), 3 half-tiles in flight, counted vmcnt(12) (never drained
// in-loop), 8 waves (2m x 4n, 64x64 each), setprio around the MFMA cluster.
// A stays fp32 in LDS (cvt_pk at read); both operands staged by gll16 DMA
// with both-sides XOR chunk swizzle (A: ^row&7, B: ^(row>>1)&3).
__global__ __launch_bounds__(512, 2) void k_gemm1(const float* __restrict__ A,
        const uint16_t* __restrict__ W1t, const float* __restrict__ bias1,
        uint16_t* __restrict__ H) {
    __shared__ float    lds_a[4][BM * 32];   // 4 x 16KB = 64KB
    __shared__ uint16_t lds_b[4][BN * 32];   // 4 x 16KB = 64KB

    const int bid = blockIdx.x;
    const int tt = (bid & 7) * WGPX1 + (bid >> 3);   // XCD-chunked; n fastest
    if (tt >= NWG1) return;
    const int m0 = (tt >> 1) * BM, n0 = (tt & 1) * BN;

    const int t = threadIdx.x, lane = t & 63, wv = t >> 6;
    const int wm = wv >> 2, wn = wv & 3;             // 2 x 4 wave grid
    const int cl = lane & 15, kh = lane >> 4;
    const int l3 = lane >> 3, l7 = lane & 7;

    // --- A staging: instr i (0,1) covers rows wv*16 + i*8 + l3, phys 4-f32
    //     chunk l7; source logical chunk = l7 ^ (row&7) = l7 ^ l3.
    const float* aS[2];
    #pragma unroll
    for (int i = 0; i < 2; ++i) {
        int r = m0 + wv * 16 + i * 8 + l3;
        if (r >= N_NODES) r = N_NODES - 1;           // tail clamp (stores guarded)
        aS[i] = A + (size_t)r * K1 + ((l7 ^ l3) * 4);
    }
    // --- B staging: instr i covers rows wv*32 + i*16 + (lane>>2), phys 8-bf16
    //     chunk lane&3; source logical chunk = (lane&3) ^ ((row>>1)&3)
    //     = (lane&3) ^ ((lane>>3)&3).
    const uint16_t* bS[2];
    #pragma unroll
    for (int i = 0; i < 2; ++i)
        bS[i] = W1t + (size_t)(n0 + wv * 32 + i * 16 + (lane >> 2)) * K1
                    + (((lane & 3) ^ ((lane >> 3) & 3)) * 8);

    // --- fragment read offsets.
    // A: row = wm*64 + mf*16 + cl, row&7 == cl&7; logical chunks 2kh, 2kh+1.
    const int q7 = cl & 7;
    const int pa0 = ((2 * kh) ^ q7) * 4, pa1 = ((2 * kh + 1) ^ q7) * 4;
    const int arow = (wm * 64 + cl) * 32;            // + mf*512
    // B: row = wn*64 + nf*16 + cl, (row>>1)&3 == (cl>>1)&3; logical chunk kh.
    const int brow = (wn * 64 + cl) * 32 + ((kh ^ ((cl >> 1) & 3)) * 8);  // + nf*512

    f32x4 acc[4][4];
    const f32x4 z = {0.f, 0.f, 0.f, 0.f};
    #pragma unroll
    for (int m = 0; m < 4; ++m)
        #pragma unroll
        for (int n = 0; n < 4; ++n) acc[m][n] = z;

#define STAGE(h) do {                                                          \
    const int b_ = (h) & 3;                                                    \
    gll16(aS[0] + (h) * 32, &lds_a[b_][wv * 512]);                             \
    gll16(aS[1] + (h) * 32, &lds_a[b_][wv * 512 + 256]);                       \
    gll16(bS[0] + (h) * 32, &lds_b[b_][wv * 1024]);                            \
    gll16(bS[1] + (h) * 32, &lds_b[b_][wv * 1024 + 512]);                      \
    } while (0)

#define COMPUTE(h) do {                                                        \
    const float*    la_ = &lds_a[(h) & 3][0];                                  \
    const uint16_t* lb_ = &lds_b[(h) & 3][0];                                  \
    bf16x8 af_[4], bq_[4];                                                     \
    _Pragma("unroll")                                                          \
    for (int nf = 0; nf < 4; ++nf)                                             \
        bq_[nf] = *(const bf16x8*)&lb_[brow + nf * 512];                       \
    _Pragma("unroll")                                                          \
    for (int mf = 0; mf < 4; ++mf) {                                           \
        f32x4 r0 = *(const f32x4*)&la_[arow + mf * 512 + pa0];                 \
        f32x4 r1 = *(const f32x4*)&la_[arow + mf * 512 + pa1];                 \
        uint32_t uu_[4];                                                       \
        uu_[0] = cvt_pk_bf16(r0[0], r0[1]);                                    \
        uu_[1] = cvt_pk_bf16(r0[2], r0[3]);                                    \
        uu_[2] = cvt_pk_bf16(r1[0], r1[1]);                                    \
        uu_[3] = cvt_pk_bf16(r1[2], r1[3]);                                    \
        af_[mf] = *(const bf16x8*)uu_;                                         \
    }                                                                          \
    __builtin_amdgcn_s_setprio(1);                                             \
    _Pragma("unroll")                                                          \
    for (int mf = 0; mf < 4; ++mf)                                             \
        _Pragma("unroll")                                                      \
        for (int nf = 0; nf < 4; ++nf)                                         \
            acc[mf][nf] = __builtin_amdgcn_mfma_f32_16x16x32_bf16(             \
                              af_[mf], bq_[nf], acc[mf][nf], 0, 0, 0);         \
    __builtin_amdgcn_s_setprio(0);                                             \
    } while (0)

// after compute: pin cluster, retire this wave's ds_reads, then free-barrier
#define READS_DONE_BARRIER() do {                                              \
    __builtin_amdgcn_sched_barrier(0);                                         \
    asm volatile("s_waitcnt lgkmcnt(0)" ::: "memory");                         \
    __builtin_amdgcn_s_barrier();                                              \
    } while (0)

    // ---- prologue: 3 half-tiles in flight (12 outstanding VMEM/wave)
    STAGE(0); STAGE(1); STAGE(2);

    // ---- steady state: h = 0..20 (STAGE(h+3) always in range)
    for (int h = 0; h < HALVES - 3; ++h) {
        STAGE(h + 3);                                    // into HB[(h-1)&3], freed last iter
        asm volatile("s_waitcnt vmcnt(12)" ::: "memory"); // stage(h) landed
        __builtin_amdgcn_s_barrier();                    // all waves: HB[h&3] ready
        COMPUTE(h);
        READS_DONE_BARRIER();                            // HB[h&3] free
    }
    // ---- tail: h = 21, 22, 23 (drain 8 -> 4 -> 0)
    asm volatile("s_waitcnt vmcnt(8)" ::: "memory");
    __builtin_amdgcn_s_barrier();
    COMPUTE(21);
    READS_DONE_BARRIER();
    asm volatile("s_waitcnt vmcnt(4)" ::: "memory");
    __builtin_amdgcn_s_barrier();
    COMPUTE(22);
    READS_DONE_BARRIER();
    asm volatile("s_waitcnt vmcnt(0)" ::: "memory");
    __builtin_amdgcn_s_barrier();
    COMPUTE(23);

#undef STAGE
#undef COMPUTE
#undef READS_DONE_BARRIER

    // ---- epilogue: +bias, relu, bf16 store. C layout: col=lane&15, row=(lane>>4)*4+reg
    float bv[4]; int bcol[4];
    #pragma unroll
    for (int n = 0; n < 4; ++n) { bcol[n] = n0 + wn * 64 + n * 16 + cl; bv[n] = bias1[bcol[n]]; }
    #pragma unroll
    for (int m = 0; m < 4; ++m) {
        int rbase = m0 + wm * 64 + m * 16 + kh * 4;
        #pragma unroll
        for (int rr = 0; rr < 4; ++rr) {
            int row = rbase + rr;
            if (row < N_NODES) {
                #pragma unroll
                for (int n = 0; n < 4; ++n) {
                    float v = acc[m][n][rr] + bv[n];
                    H[(size_t)row * D1 + bcol[n]] = f2bf(fmaxf(v, 0.f));
                }
            }
        }
    }
}

// ---- GEMM2: out[16384][97] = concat(H[head], H[tail]) @ Wp + bp ----
// (reverted to the proven LDS-staged version — R13 showed direct-global is slower)
__global__ __launch_bounds__(256) void k_gemm2(const uint16_t* __restrict__ H,
        const uint16_t* __restrict__ Wpt, const float* __restrict__ bp,
        const int* __restrict__ head, const int* __restrict__ tail,
        float* __restrict__ out) {
    __shared__ uint16_t lds_w[NOUT_PAD][40];
    const int t = threadIdx.x;
    const int lane = t & 63, wave = t >> 6;
    const int cl = lane & 15, kh = lane >> 4;
    const int rowbase = blockIdx.x * 64 + wave * 16;
    const int i_l = rowbase + cl;
    const int nodeH = head[i_l], nodeT = tail[i_l];
    const uint16_t* hH = H + (size_t)nodeH * D1 + kh * 8;
    const uint16_t* hT = H + (size_t)nodeT * D1 + kh * 8;

    f32x4 acc[7];
    const f32x4 z = {0.f, 0.f, 0.f, 0.f};
    #pragma unroll
    for (int n = 0; n < 7; ++n) acc[n] = z;

    const int wrow = t >> 1, whalf = t & 1;
    const uint16_t* wsrc = Wpt + (size_t)wrow * 1024 + whalf * 16;
    uint16_t* wdst = &lds_w[wrow][whalf * 16];

    for (int kb = 0; kb < 32; ++kb) {
        uint4 w0 = {0,0,0,0}, w1 = {0,0,0,0};
        if (t < 224) {
            const uint4* wp4 = (const uint4*)(wsrc + kb * 32);
            w0 = wp4[0]; w1 = wp4[1];
        }
        bf16x8 af = (kb < 16) ? *(const bf16x8*)(hH + kb * 32)
                              : *(const bf16x8*)(hT + (kb - 16) * 32);
        __syncthreads();
        if (t < 224) { ((uint4*)wdst)[0] = w0; ((uint4*)wdst)[1] = w1; }
        __syncthreads();
        #pragma unroll
        for (int n = 0; n < 7; ++n) {
            bf16x8 bfr = *(const bf16x8*)&lds_w[n * 16 + cl][kh * 8];
            acc[n] = __builtin_amdgcn_mfma_f32_16x16x32_bf16(af, bfr, acc[n], 0, 0, 0);
        }
    }
    #pragma unroll
    for (int n = 0; n < 7; ++n) {
        int col = n * 16 + cl;
        if (col < NOUT) {
            float bb = bp[col];
            #pragma unroll
            for (int rr = 0; rr < 4; ++rr) {
                int i = rowbase + kh * 4 + rr;
                out[(size_t)i * NOUT + col] = acc[n][rr] + bb;
            }
        }
    }
}

extern "C" void kernel_launch(void* const* d_in, const int* in_sizes, int n_in,
                              void* d_out, int out_size, void* d_ws, size_t ws_size,
                              hipStream_t stream) {
    const float* node_features = (const float*)d_in[0];
    // d_in[1] = edge_features (unused: message passing is an exact identity)
    const float* W1   = (const float*)d_in[2];
    const float* b1   = (const float*)d_in[3];
    const float* Wp   = (const float*)d_in[4];
    const float* bp   = (const float*)d_in[5];
    // d_in[6] = src (unused), d_in[7] = dst (unused)
    const int* head   = (const int*)d_in[8];
    const int* tail   = (const int*)d_in[9];
    float* out = (float*)d_out;

    char* ws = (char*)d_ws;
    uint16_t* H   = (uint16_t*)ws;
    uint16_t* W1t = (uint16_t*)(ws + (size_t)N_NODES * D1 * 2);
    uint16_t* Wpt = (uint16_t*)(ws + (size_t)N_NODES * D1 * 2 + (size_t)D1 * K1 * 2);

    const int convN = D1 * K1 + NOUT_PAD * 1024;
    k_convert<<<(convN + 255) / 256, 256, 0, stream>>>(W1, Wp, W1t, Wpt);

    k_gemm1<<<WGPX1 * 8, 512, 0, stream>>>(node_features, W1t, b1, H);

    k_gemm2<<<NPAIR / 64, 256, 0, stream>>>(H, Wpt, bp, head, tail, out);
}

// Round 15
// 104.732 us; speedup vs baseline: 1.3241x; 1.3241x over previous
//
#include <hip/hip_runtime.h>
#include <hip/hip_bf16.h>
#include <stdint.h>

using bf16x8 = __attribute__((ext_vector_type(8))) short;
using f32x4  = __attribute__((ext_vector_type(4))) float;
typedef float f32x4u __attribute__((ext_vector_type(4), aligned(4)));  // 4B-aligned vec store

#define N_NODES  50000
#define K1       768
#define D1       512
#define NPAIR    16384
#define NOUT     97
#define NOUT_PAD 112
#define MTILES   391                 // ceil(50000/128)
#define NTILES   4
#define NWG      (MTILES * NTILES)   // 1564
#define WGPX     196                 // ceil(1564/8)
#define KSTEPS   24                  // 768/32

__device__ __forceinline__ uint16_t f2bf(float f) {
    uint32_t u = __builtin_bit_cast(uint32_t, f);
    return (uint16_t)((u + 0x7fffu + ((u >> 16) & 1u)) >> 16);  // RNE
}

__device__ __forceinline__ uint32_t cvt_pk_bf16(float lo, float hi) {
    uint32_t r;
    asm("v_cvt_pk_bf16_f32 %0, %1, %2" : "=v"(r) : "v"(lo), "v"(hi));
    return r;
}

// async global->LDS DMA, 16B/lane; LDS dest = wave-uniform base + lane*16
__device__ __forceinline__ void gll16(const void* g, void* l) {
    __builtin_amdgcn_global_load_lds(
        (const __attribute__((address_space(1))) void*)g,
        (__attribute__((address_space(3))) void*)l, 16, 0, 0);
}

// ---- convert (coalesced 32x32 LDS transpose):
//   W1[768][512] -> W1t bf16 [512][768]   (blocks 0..383:  24 k-tiles x 16 c-tiles)
//   Wp[1024][97] -> Wpt bf16 [112][1024]  (blocks 384..511: 32 k-tiles x 4 c-tiles, zero-pad)
__global__ __launch_bounds__(256) void k_convert(const float* __restrict__ W1,
        const float* __restrict__ Wp, uint16_t* __restrict__ W1t, uint16_t* __restrict__ Wpt) {
    __shared__ uint16_t lds[32][34];
    const int t = threadIdx.x;
    const int b = blockIdx.x;
    const int lane = t & 31, rw = t >> 5;       // read phase: lane = col, rw+j*8 = row
    const int lane16 = t & 15, rw2 = t >> 4;    // write phase

    if (b < 384) {
        const int kt = b % 24, ct = b / 24;
        const int k0 = kt * 32, c0 = ct * 32;
        #pragma unroll
        for (int j = 0; j < 4; ++j) {
            int k = rw + j * 8;
            lds[lane][k] = f2bf(W1[(size_t)(k0 + k) * D1 + c0 + lane]);  // coalesced read
        }
        __syncthreads();
        #pragma unroll
        for (int j = 0; j < 2; ++j) {
            int c = rw2 + j * 16;
            uint32_t v = (uint32_t)lds[c][lane16 * 2] | ((uint32_t)lds[c][lane16 * 2 + 1] << 16);
            *(uint32_t*)&W1t[(size_t)(c0 + c) * K1 + k0 + lane16 * 2] = v;  // coalesced write
        }
    } else {
        const int b2 = b - 384;
        const int kt = b2 % 32, ct = b2 / 32;
        const int k0 = kt * 32, c0 = ct * 32;
        #pragma unroll
        for (int j = 0; j < 4; ++j) {
            int k = rw + j * 8;
            float v = (c0 + lane < NOUT) ? Wp[(size_t)(k0 + k) * NOUT + c0 + lane] : 0.f;
            lds[lane][k] = f2bf(v);
        }
        __syncthreads();
        #pragma unroll
        for (int j = 0; j < 2; ++j) {
            int c = rw2 + j * 16;
            if (c0 + c < NOUT_PAD) {
                uint32_t v = (uint32_t)lds[c][lane16 * 2] | ((uint32_t)lds[c][lane16 * 2 + 1] << 16);
                *(uint32_t*)&Wpt[(size_t)(c0 + c) * 1024 + k0 + lane16 * 2] = v;
            }
        }
    }
}

// ---- GEMM1: H[50000][512] = relu(A @ W1 + b1) ----
// R6 structure (proven, best total): 128x128 tile, BK=32, 8 waves (4m x 2wn),
// gll16 double-buffered staging, counted vmcnt(3), chunk-XOR swizzles.
// NEW: swapped MFMA operands -> per-lane acc spans 4 CONSECUTIVE H-columns,
// epilogue packs via cvt_pk into 8x 8-byte stores (was 32x 2-byte scalar).
__global__ __launch_bounds__(512) void k_gemm1(const float* __restrict__ A,
        const uint16_t* __restrict__ W1t, const float* __restrict__ bias1,
        uint16_t* __restrict__ H) {
    __shared__ float    lds_a[2 * 4096];   // 2 x (128 rows x 32 fp32)
    __shared__ uint16_t lds_b[2 * 4096];   // 2 x (128 rows x 32 bf16)

    const int bid = blockIdx.x;
    const int tt = (bid & 7) * WGPX + (bid >> 3);
    if (tt >= NWG) return;
    const int m0 = (tt >> 2) * 128, n0 = (tt & 3) * 128;

    const int t = threadIdx.x, lane = t & 63, w = t >> 6;
    const int wm = w >> 1, wn = w & 1;            // 4 x 2 wave grid
    const int cl = lane & 15, kh = lane >> 4;

    // --- A staging: instr i (i=0,1) covers rows i*64 + (t>>3), phys chunk t&7.
    const float* aSrc[2];
    #pragma unroll
    for (int i = 0; i < 2; ++i) {
        int r = m0 + i * 64 + (t >> 3);
        if (r >= N_NODES) r = N_NODES - 1;        // tail clamp (stores guarded)
        aSrc[i] = A + (size_t)r * K1 + (((t & 7) ^ ((t >> 3) & 7)) * 4);
    }
    // --- B staging: covers rows t>>2, phys chunk t&3; pre-swizzled source.
    const uint16_t* bSrc =
        W1t + (size_t)(n0 + (t >> 2)) * K1 + (((t & 3) ^ ((t >> 3) & 3)) * 8);

    float*    aDst = &lds_a[w * 256];
    uint16_t* bDst = &lds_b[w * 512];

    // --- fragment read offsets (identical to R6)
    const int q7 = cl & 7;
    const int pa0 = ((2 * kh) ^ q7) * 4, pa1 = ((2 * kh + 1) ^ q7) * 4;
    const int arow0 = (wm * 32 + cl) * 32;
    const int brow0 = (wn * 64 + cl) * 32 + ((kh ^ ((cl >> 1) & 3)) * 8);

    f32x4 acc[2][4];
    const f32x4 z = {0.f, 0.f, 0.f, 0.f};
    #pragma unroll
    for (int m = 0; m < 2; ++m)
        #pragma unroll
        for (int n = 0; n < 4; ++n) acc[m][n] = z;

#define STAGE(BUF) do {                                                        \
    gll16(aSrc[0], aDst + (BUF) * 4096);                                       \
    gll16(aSrc[1], aDst + (BUF) * 4096 + 2048);                                \
    gll16(bSrc,    bDst + (BUF) * 4096);                                       \
    aSrc[0] += 32; aSrc[1] += 32; bSrc += 32;                                  \
    } while (0)

// swapped operands: acc = mfma(bq, af) -> D rows = H-cols, D col(lane)=H-row
#define COMPUTE(BUF) do {                                                      \
    const float*    la = &lds_a[(BUF) * 4096];                                 \
    const uint16_t* lb = &lds_b[(BUF) * 4096];                                 \
    bf16x8 bfr[4];                                                             \
    _Pragma("unroll")                                                          \
    for (int n = 0; n < 4; ++n)                                                \
        bfr[n] = *(const bf16x8*)&lb[brow0 + n * 512];                         \
    _Pragma("unroll")                                                          \
    for (int m = 0; m < 2; ++m) {                                              \
        f32x4 r0 = *(const f32x4*)&la[arow0 + m * 512 + pa0];                  \
        f32x4 r1 = *(const f32x4*)&la[arow0 + m * 512 + pa1];                  \
        uint32_t uu[4];                                                        \
        uu[0] = cvt_pk_bf16(r0[0], r0[1]);                                     \
        uu[1] = cvt_pk_bf16(r0[2], r0[3]);                                     \
        uu[2] = cvt_pk_bf16(r1[0], r1[1]);                                     \
        uu[3] = cvt_pk_bf16(r1[2], r1[3]);                                     \
        bf16x8 af = *(const bf16x8*)uu;                                        \
        _Pragma("unroll")                                                      \
        for (int n = 0; n < 4; ++n)                                            \
            acc[m][n] = __builtin_amdgcn_mfma_f32_16x16x32_bf16(               \
                            bfr[n], af, acc[m][n], 0, 0, 0);                   \
    }                                                                          \
    } while (0)

    STAGE(0);   // prologue: K-step 0 in flight (3 loads outstanding)
    for (int kt = 0; kt < KSTEPS - 1; ++kt) {
        const int cur = kt & 1;
        STAGE(cur ^ 1);                                  // issue kt+1 (3 loads)
        asm volatile("s_waitcnt vmcnt(3)" ::: "memory"); // kt's 3 loads landed
        __builtin_amdgcn_s_barrier();                    // all waves: tile ready
        COMPUTE(cur);
        __builtin_amdgcn_sched_barrier(0);               // pin cluster (rule #18)
        asm volatile("s_waitcnt lgkmcnt(0)" ::: "memory");
        __builtin_amdgcn_s_barrier();                    // reads done -> buf free
    }
    asm volatile("s_waitcnt vmcnt(0)" ::: "memory");
    __builtin_amdgcn_s_barrier();
    COMPUTE((KSTEPS - 1) & 1);

#undef STAGE
#undef COMPUTE

    // ---- epilogue (swapped layout): H-row = m0 + wm*32 + mf*16 + cl;
    //      H-cols = n0 + wn*64 + nf*16 + kh*4 + {0..3}  (consecutive!)
    float4 bb[4];
    #pragma unroll
    for (int nf = 0; nf < 4; ++nf)
        bb[nf] = *(const float4*)&bias1[n0 + wn * 64 + nf * 16 + kh * 4];
    #pragma unroll
    for (int mf = 0; mf < 2; ++mf) {
        int row = m0 + wm * 32 + mf * 16 + cl;
        if (row < N_NODES) {
            uint16_t* hp = H + (size_t)row * D1 + n0 + wn * 64 + kh * 4;
            #pragma unroll
            for (int nf = 0; nf < 4; ++nf) {
                float v0 = fmaxf(acc[mf][nf][0] + bb[nf].x, 0.f);
                float v1 = fmaxf(acc[mf][nf][1] + bb[nf].y, 0.f);
                float v2 = fmaxf(acc[mf][nf][2] + bb[nf].z, 0.f);
                float v3 = fmaxf(acc[mf][nf][3] + bb[nf].w, 0.f);
                uint2 pk = { cvt_pk_bf16(v0, v1), cvt_pk_bf16(v2, v3) };
                *(uint2*)(hp + nf * 16) = pk;
            }
        }
    }
}

// ---- GEMM2: out[16384][97] = concat(H[head], H[tail]) @ Wp + bp ----
// LDS-staged (proven). NEW: swapped MFMA operands -> per-lane out-row = rowbase+cl,
// out-cols consecutive -> float4-class stores (was 28 scalar stores).
__global__ __launch_bounds__(256) void k_gemm2(const uint16_t* __restrict__ H,
        const uint16_t* __restrict__ Wpt, const float* __restrict__ bp,
        const int* __restrict__ head, const int* __restrict__ tail,
        float* __restrict__ out) {
    __shared__ uint16_t lds_w[NOUT_PAD][40];
    const int t = threadIdx.x;
    const int lane = t & 63, wave = t >> 6;
    const int cl = lane & 15, kh = lane >> 4;
    const int rowbase = blockIdx.x * 64 + wave * 16;
    const int i_l = rowbase + cl;
    const int nodeH = head[i_l], nodeT = tail[i_l];
    const uint16_t* hH = H + (size_t)nodeH * D1 + kh * 8;
    const uint16_t* hT = H + (size_t)nodeT * D1 + kh * 8;

    f32x4 acc[7];
    const f32x4 z = {0.f, 0.f, 0.f, 0.f};
    #pragma unroll
    for (int n = 0; n < 7; ++n) acc[n] = z;

    const int wrow = t >> 1, whalf = t & 1;
    const uint16_t* wsrc = Wpt + (size_t)wrow * 1024 + whalf * 16;
    uint16_t* wdst = &lds_w[wrow][whalf * 16];

    for (int kb = 0; kb < 32; ++kb) {
        uint4 w0 = {0,0,0,0}, w1 = {0,0,0,0};
        if (t < 224) {
            const uint4* wp4 = (const uint4*)(wsrc + kb * 32);
            w0 = wp4[0]; w1 = wp4[1];
        }
        bf16x8 af = (kb < 16) ? *(const bf16x8*)(hH + kb * 32)
                              : *(const bf16x8*)(hT + (kb - 16) * 32);
        __syncthreads();
        if (t < 224) { ((uint4*)wdst)[0] = w0; ((uint4*)wdst)[1] = w1; }
        __syncthreads();
        #pragma unroll
        for (int n = 0; n < 7; ++n) {
            bf16x8 bfr = *(const bf16x8*)&lds_w[n * 16 + cl][kh * 8];
            acc[n] = __builtin_amdgcn_mfma_f32_16x16x32_bf16(bfr, af, acc[n], 0, 0, 0);
        }
    }

    // swapped layout: out-row = rowbase + cl; out-cols = n*16 + kh*4 + {0..3}
    float* op = out + (size_t)(rowbase + cl) * NOUT;
    #pragma unroll
    for (int n = 0; n < 7; ++n) {
        int cb = n * 16 + kh * 4;
        if (cb + 3 < NOUT) {
            float4 bbv = *(const float4*)&bp[cb];
            f32x4u v = { acc[n][0] + bbv.x, acc[n][1] + bbv.y,
                         acc[n][2] + bbv.z, acc[n][3] + bbv.w };
            *(f32x4u*)(op + cb) = v;
        } else if (cb < NOUT) {
            #pragma unroll
            for (int rr = 0; rr < 4; ++rr)
                if (cb + rr < NOUT) op[cb + rr] = acc[n][rr] + bp[cb + rr];
        }
    }
}

extern "C" void kernel_launch(void* const* d_in, const int* in_sizes, int n_in,
                              void* d_out, int out_size, void* d_ws, size_t ws_size,
                              hipStream_t stream) {
    const float* node_features = (const float*)d_in[0];
    // d_in[1] = edge_features (unused: message passing is an exact identity)
    const float* W1   = (const float*)d_in[2];
    const float* b1   = (const float*)d_in[3];
    const float* Wp   = (const float*)d_in[4];
    const float* bp   = (const float*)d_in[5];
    // d_in[6] = src (unused), d_in[7] = dst (unused)
    const int* head   = (const int*)d_in[8];
    const int* tail   = (const int*)d_in[9];
    float* out = (float*)d_out;

    char* ws = (char*)d_ws;
    uint16_t* H   = (uint16_t*)ws;
    uint16_t* W1t = (uint16_t*)(ws + (size_t)N_NODES * D1 * 2);
    uint16_t* Wpt = (uint16_t*)(ws + (size_t)N_NODES * D1 * 2 + (size_t)D1 * K1 * 2);

    k_convert<<<512, 256, 0, stream>>>(W1, Wp, W1t, Wpt);

    k_gemm1<<<WGPX * 8, 512, 0, stream>>>(node_features, W1t, b1, H);

    k_gemm2<<<NPAIR / 64, 256, 0, stream>>>(H, Wpt, bp, head, tail, out);
}

// Round 16
// 99.106 us; speedup vs baseline: 1.3993x; 1.0568x over previous
//
#include <hip/hip_runtime.h>
#include <hip/hip_bf16.h>
#include <stdint.h>

using bf16x8 = __attribute__((ext_vector_type(8))) short;
using f32x4  = __attribute__((ext_vector_type(4))) float;
typedef float f32x4u __attribute__((ext_vector_type(4), aligned(4)));  // 4B-aligned vec store

#define N_NODES  50000
#define K1       768
#define D1       512
#define NPAIR    16384
#define NOUT     97
#define NOUT_PAD 112
#define MTILES   391                 // ceil(50000/128)
#define NTILES   4
#define NWG      (MTILES * NTILES)   // 1564
#define WGPX     196                 // ceil(1564/8)
#define KSTEPS   24                  // 768/32

__device__ __forceinline__ uint16_t f2bf(float f) {
    uint32_t u = __builtin_bit_cast(uint32_t, f);
    return (uint16_t)((u + 0x7fffu + ((u >> 16) & 1u)) >> 16);  // RNE
}

__device__ __forceinline__ uint32_t cvt_pk_bf16(float lo, float hi) {
    uint32_t r;
    asm("v_cvt_pk_bf16_f32 %0, %1, %2" : "=v"(r) : "v"(lo), "v"(hi));
    return r;
}

// async global->LDS DMA, 16B/lane; LDS dest = wave-uniform base + lane*16
__device__ __forceinline__ void gll16(const void* g, void* l) {
    __builtin_amdgcn_global_load_lds(
        (const __attribute__((address_space(1))) void*)g,
        (__attribute__((address_space(3))) void*)l, 16, 0, 0);
}

// ---- convert (coalesced 32x32 LDS transpose):
//   W1[768][512] -> W1t bf16 [512][768]   (blocks 0..383:  24 k-tiles x 16 c-tiles)
//   Wp[1024][97] -> Wpt bf16 [112][1024]  (blocks 384..511: 32 k-tiles x 4 c-tiles, zero-pad)
__global__ __launch_bounds__(256) void k_convert(const float* __restrict__ W1,
        const float* __restrict__ Wp, uint16_t* __restrict__ W1t, uint16_t* __restrict__ Wpt) {
    __shared__ uint16_t lds[32][34];
    const int t = threadIdx.x;
    const int b = blockIdx.x;
    const int lane = t & 31, rw = t >> 5;       // read phase: lane = col, rw+j*8 = row
    const int lane16 = t & 15, rw2 = t >> 4;    // write phase

    if (b < 384) {
        const int kt = b % 24, ct = b / 24;
        const int k0 = kt * 32, c0 = ct * 32;
        #pragma unroll
        for (int j = 0; j < 4; ++j) {
            int k = rw + j * 8;
            lds[lane][k] = f2bf(W1[(size_t)(k0 + k) * D1 + c0 + lane]);  // coalesced read
        }
        __syncthreads();
        #pragma unroll
        for (int j = 0; j < 2; ++j) {
            int c = rw2 + j * 16;
            uint32_t v = (uint32_t)lds[c][lane16 * 2] | ((uint32_t)lds[c][lane16 * 2 + 1] << 16);
            *(uint32_t*)&W1t[(size_t)(c0 + c) * K1 + k0 + lane16 * 2] = v;  // coalesced write
        }
    } else {
        const int b2 = b - 384;
        const int kt = b2 % 32, ct = b2 / 32;
        const int k0 = kt * 32, c0 = ct * 32;
        #pragma unroll
        for (int j = 0; j < 4; ++j) {
            int k = rw + j * 8;
            float v = (c0 + lane < NOUT) ? Wp[(size_t)(k0 + k) * NOUT + c0 + lane] : 0.f;
            lds[lane][k] = f2bf(v);
        }
        __syncthreads();
        #pragma unroll
        for (int j = 0; j < 2; ++j) {
            int c = rw2 + j * 16;
            if (c0 + c < NOUT_PAD) {
                uint32_t v = (uint32_t)lds[c][lane16 * 2] | ((uint32_t)lds[c][lane16 * 2 + 1] << 16);
                *(uint32_t*)&Wpt[(size_t)(c0 + c) * 1024 + k0 + lane16 * 2] = v;
            }
        }
    }
}

// ---- GEMM1: H[50000][512] = relu(A @ W1 + b1) ----
// 128x128 tile, BK=32, 8 waves. NEW vs R15: A staged as BF16 (reg-cvt, one 16B
// ds_write/thread) -> LDS 32KB/block -> 3 blocks/CU (m97's TLP regime). COMPUTE
// = 6 ds_read_b128 + 8 MFMA, no in-loop cvt. Counted vmcnt(1)/iter; A-loads get
// a full iteration of flight. Swizzle: chunk ^ ((row>>1)&3), both sides.
__global__ __launch_bounds__(512, 6) void k_gemm1(const float* __restrict__ A,
        const uint16_t* __restrict__ W1t, const float* __restrict__ bias1,
        uint16_t* __restrict__ H) {
    __shared__ uint16_t lds_a[2][128 * 32];   // bf16 A tiles, 8KB each
    __shared__ uint16_t lds_b[2][128 * 32];   // bf16 B tiles, 8KB each

    const int bid = blockIdx.x;
    const int tt = (bid & 7) * WGPX + (bid >> 3);
    if (tt >= NWG) return;
    const int m0 = (tt >> 2) * 128, n0 = (tt & 3) * 128;

    const int t = threadIdx.x, lane = t & 63, w = t >> 6;
    const int wm = w >> 1, wn = w & 1;            // 4 x 2 wave grid
    const int cl = lane & 15, kh = lane >> 4;

    // --- A staging (reg->cvt->ds_write): thread t covers row t>>2, logical
    //     8-float chunk t&3; LDS write at phys chunk (t&3) ^ ((row>>1)&3).
    int arow_g = m0 + (t >> 2); if (arow_g >= N_NODES) arow_g = N_NODES - 1;
    const float* aSrc = A + (size_t)arow_g * K1 + (t & 3) * 8;
    const int aWrOff = (t >> 2) * 32 + (((t & 3) ^ ((t >> 3) & 3)) * 8);

    // --- B staging (DMA, byte-identical to R15): wave w dest = lds_b[buf]+w*512,
    //     lane's 16B lands at row w*16+(lane>>2), phys chunk lane&3; source
    //     logical chunk pre-swizzled.
    const uint16_t* bSrc =
        W1t + (size_t)(n0 + (t >> 2)) * K1 + (((t & 3) ^ ((t >> 3) & 3)) * 8);

    // --- fragment read chunk offset: phys = kh ^ ((row>>1)&3), (row>>1)&3 == (cl>>1)&3
    const int fo = (kh ^ ((cl >> 1) & 3)) * 8;

    f32x4 acc[2][4];
    const f32x4 z = {0.f, 0.f, 0.f, 0.f};
    #pragma unroll
    for (int m = 0; m < 2; ++m)
        #pragma unroll
        for (int n = 0; n < 4; ++n) acc[m][n] = z;

    float4 rA0, rA1;   // next A tile, raw fp32

#define WRITE_A(BUF, R0, R1) do {                                              \
    uint32_t u0_ = cvt_pk_bf16((R0).x, (R0).y);                                \
    uint32_t u1_ = cvt_pk_bf16((R0).z, (R0).w);                                \
    uint32_t u2_ = cvt_pk_bf16((R1).x, (R1).y);                                \
    uint32_t u3_ = cvt_pk_bf16((R1).z, (R1).w);                                \
    uint4 v_ = {u0_, u1_, u2_, u3_};                                           \
    *(uint4*)&lds_a[BUF][aWrOff] = v_;                                         \
    } while (0)

// swapped operands (R15): acc = mfma(bq, af) -> per-lane acc = 4 consecutive H-cols
#define COMPUTE(BUF) do {                                                      \
    const uint16_t* la_ = &lds_a[BUF][0];                                      \
    const uint16_t* lb_ = &lds_b[BUF][0];                                      \
    bf16x8 af_[2], bq_[4];                                                     \
    _Pragma("unroll")                                                          \
    for (int nf = 0; nf < 4; ++nf)                                             \
        bq_[nf] = *(const bf16x8*)&lb_[(wn * 64 + nf * 16 + cl) * 32 + fo];    \
    _Pragma("unroll")                                                          \
    for (int mf = 0; mf < 2; ++mf)                                             \
        af_[mf] = *(const bf16x8*)&la_[(wm * 32 + mf * 16 + cl) * 32 + fo];    \
    _Pragma("unroll")                                                          \
    for (int mf = 0; mf < 2; ++mf)                                             \
        _Pragma("unroll")                                                      \
        for (int nf = 0; nf < 4; ++nf)                                         \
            acc[mf][nf] = __builtin_amdgcn_mfma_f32_16x16x32_bf16(             \
                              bq_[nf], af_[mf], acc[mf][nf], 0, 0, 0);         \
    } while (0)

    // ---- prologue: tile 0 staged; rA holds A(1)
    gll16(bSrc, &lds_b[0][w * 512]);                       // B(0)
    {
        float4 t0 = *(const float4*)(aSrc);
        float4 t1 = *(const float4*)(aSrc + 4);            // A(0)
        asm volatile("s_waitcnt vmcnt(0)" ::: "memory");   // A(0)+B(0) landed
        WRITE_A(0, t0, t1);
    }
    rA0 = *(const float4*)(aSrc + 32);
    rA1 = *(const float4*)(aSrc + 36);                     // A(1) in flight

    // ---- steady: kt = 0..21
    for (int kt = 0; kt < 22; ++kt) {
        const int cur = kt & 1, nxt = cur ^ 1;
        gll16(bSrc + (kt + 1) * 32, &lds_b[nxt][w * 512]); // B(kt+1) -> nxt
        asm volatile("s_waitcnt vmcnt(1)" ::: "memory");   // rA(kt+1) ready; B(kt) retired
        WRITE_A(nxt, rA0, rA1);                            // A(kt+1) -> nxt
        rA0 = *(const float4*)(aSrc + (kt + 2) * 32);      // A(kt+2): full-iter flight
        rA1 = *(const float4*)(aSrc + (kt + 2) * 32 + 4);
        asm volatile("s_waitcnt lgkmcnt(0)" ::: "memory"); // my ds_write retired
        __builtin_amdgcn_s_barrier();                      // publish buf[cur]
        COMPUTE(cur);
        __builtin_amdgcn_sched_barrier(0);                 // pin cluster (rule #18)
        asm volatile("s_waitcnt lgkmcnt(0)" ::: "memory"); // my ds_reads retired
        __builtin_amdgcn_s_barrier();                      // buf[cur] free
    }
    // ---- kt = 22
    gll16(bSrc + 23 * 32, &lds_b[1][w * 512]);             // B(23) -> buf1
    asm volatile("s_waitcnt vmcnt(1)" ::: "memory");       // rA(23) ready; B(22) retired
    WRITE_A(1, rA0, rA1);                                  // A(23) -> buf1
    asm volatile("s_waitcnt lgkmcnt(0)" ::: "memory");
    __builtin_amdgcn_s_barrier();                          // publish buf0 (tile 22)
    COMPUTE(0);
    __builtin_amdgcn_sched_barrier(0);
    asm volatile("s_waitcnt lgkmcnt(0)" ::: "memory");
    __builtin_amdgcn_s_barrier();
    // ---- kt = 23
    asm volatile("s_waitcnt vmcnt(0)" ::: "memory");       // B(23) landed
    __builtin_amdgcn_s_barrier();                          // publish buf1 (tile 23)
    COMPUTE(1);

#undef WRITE_A
#undef COMPUTE

    // ---- epilogue (swapped layout, R15): H-row = m0 + wm*32 + mf*16 + cl;
    //      H-cols = n0 + wn*64 + nf*16 + kh*4 + {0..3}  (consecutive)
    float4 bb[4];
    #pragma unroll
    for (int nf = 0; nf < 4; ++nf)
        bb[nf] = *(const float4*)&bias1[n0 + wn * 64 + nf * 16 + kh * 4];
    #pragma unroll
    for (int mf = 0; mf < 2; ++mf) {
        int row = m0 + wm * 32 + mf * 16 + cl;
        if (row < N_NODES) {
            uint16_t* hp = H + (size_t)row * D1 + n0 + wn * 64 + kh * 4;
            #pragma unroll
            for (int nf = 0; nf < 4; ++nf) {
                float v0 = fmaxf(acc[mf][nf][0] + bb[nf].x, 0.f);
                float v1 = fmaxf(acc[mf][nf][1] + bb[nf].y, 0.f);
                float v2 = fmaxf(acc[mf][nf][2] + bb[nf].z, 0.f);
                float v3 = fmaxf(acc[mf][nf][3] + bb[nf].w, 0.f);
                uint2 pk = { cvt_pk_bf16(v0, v1), cvt_pk_bf16(v2, v3) };
                *(uint2*)(hp + nf * 16) = pk;
            }
        }
    }
}

// ---- GEMM2: out[16384][97] = concat(H[head], H[tail]) @ Wp + bp ----
// LDS-staged (proven). Swapped MFMA operands -> float4-class stores (R15).
__global__ __launch_bounds__(256) void k_gemm2(const uint16_t* __restrict__ H,
        const uint16_t* __restrict__ Wpt, const float* __restrict__ bp,
        const int* __restrict__ head, const int* __restrict__ tail,
        float* __restrict__ out) {
    __shared__ uint16_t lds_w[NOUT_PAD][40];
    const int t = threadIdx.x;
    const int lane = t & 63, wave = t >> 6;
    const int cl = lane & 15, kh = lane >> 4;
    const int rowbase = blockIdx.x * 64 + wave * 16;
    const int i_l = rowbase + cl;
    const int nodeH = head[i_l], nodeT = tail[i_l];
    const uint16_t* hH = H + (size_t)nodeH * D1 + kh * 8;
    const uint16_t* hT = H + (size_t)nodeT * D1 + kh * 8;

    f32x4 acc[7];
    const f32x4 z = {0.f, 0.f, 0.f, 0.f};
    #pragma unroll
    for (int n = 0; n < 7; ++n) acc[n] = z;

    const int wrow = t >> 1, whalf = t & 1;
    const uint16_t* wsrc = Wpt + (size_t)wrow * 1024 + whalf * 16;
    uint16_t* wdst = &lds_w[wrow][whalf * 16];

    for (int kb = 0; kb < 32; ++kb) {
        uint4 w0 = {0,0,0,0}, w1 = {0,0,0,0};
        if (t < 224) {
            const uint4* wp4 = (const uint4*)(wsrc + kb * 32);
            w0 = wp4[0]; w1 = wp4[1];
        }
        bf16x8 af = (kb < 16) ? *(const bf16x8*)(hH + kb * 32)
                              : *(const bf16x8*)(hT + (kb - 16) * 32);
        __syncthreads();
        if (t < 224) { ((uint4*)wdst)[0] = w0; ((uint4*)wdst)[1] = w1; }
        __syncthreads();
        #pragma unroll
        for (int n = 0; n < 7; ++n) {
            bf16x8 bfr = *(const bf16x8*)&lds_w[n * 16 + cl][kh * 8];
            acc[n] = __builtin_amdgcn_mfma_f32_16x16x32_bf16(bfr, af, acc[n], 0, 0, 0);
        }
    }

    // swapped layout: out-row = rowbase + cl; out-cols = n*16 + kh*4 + {0..3}
    float* op = out + (size_t)(rowbase + cl) * NOUT;
    #pragma unroll
    for (int n = 0; n < 7; ++n) {
        int cb = n * 16 + kh * 4;
        if (cb + 3 < NOUT) {
            float4 bbv = *(const float4*)&bp[cb];
            f32x4u v = { acc[n][0] + bbv.x, acc[n][1] + bbv.y,
                         acc[n][2] + bbv.z, acc[n][3] + bbv.w };
            *(f32x4u*)(op + cb) = v;
        } else if (cb < NOUT) {
            #pragma unroll
            for (int rr = 0; rr < 4; ++rr)
                if (cb + rr < NOUT) op[cb + rr] = acc[n][rr] + bp[cb + rr];
        }
    }
}

extern "C" void kernel_launch(void* const* d_in, const int* in_sizes, int n_in,
                              void* d_out, int out_size, void* d_ws, size_t ws_size,
                              hipStream_t stream) {
    const float* node_features = (const float*)d_in[0];
    // d_in[1] = edge_features (unused: message passing is an exact identity)
    const float* W1   = (const float*)d_in[2];
    const float* b1   = (const float*)d_in[3];
    const float* Wp   = (const float*)d_in[4];
    const float* bp   = (const float*)d_in[5];
    // d_in[6] = src (unused), d_in[7] = dst (unused)
    const int* head   = (const int*)d_in[8];
    const int* tail   = (const int*)d_in[9];
    float* out = (float*)d_out;

    char* ws = (char*)d_ws;
    uint16_t* H   = (uint16_t*)ws;
    uint16_t* W1t = (uint16_t*)(ws + (size_t)N_NODES * D1 * 2);
    uint16_t* Wpt = (uint16_t*)(ws + (size_t)N_NODES * D1 * 2 + (size_t)D1 * K1 * 2);

    k_convert<<<512, 256, 0, stream>>>(W1, Wp, W1t, Wpt);

    k_gemm1<<<WGPX * 8, 512, 0, stream>>>(node_features, W1t, b1, H);

    k_gemm2<<<NPAIR / 64, 256, 0, stream>>>(H, Wpt, bp, head, tail, out);
}